// Round 8
// baseline (1050.340 us; speedup 1.0000x reference)
//
#include <hip/hip_runtime.h>

#define BB 8
#define SS 128
#define NN 64
#define DKK 256
#define HH 8
#define DHH 32
#define OUT0_ELEMS 16777216   // B*S*N*DK
// weights elems: B*H*S*N*N = 33554432

typedef unsigned short u16;
typedef __attribute__((ext_vector_type(8))) short short8;   // 8 bf16 (4 VGPRs)
typedef __attribute__((ext_vector_type(4))) float f32x4;    // MFMA C/D frag

// ws layout: [0,512) flag; [512,1MiB+512) WT hi(4x128K)+lo(4x128K);
// [2MiB, 2MiB+192MiB) projected QKV f32 (3 x 16777216 floats).
#define WS_WT 1049088ull
#define XQ_OFF 2097152ull
#define WS_FULL 203423744ull   // 2MiB + 3*64MiB

__device__ __forceinline__ float bf2f(u16 u) {
    union { unsigned int ui; float f; } c;
    c.ui = ((unsigned int)u) << 16;
    return c.f;
}
__device__ __forceinline__ u16 f2bf(float f) {
    union { float f; unsigned int u; } c;
    c.f = f;
    unsigned int u = c.u;
    return (u16)((u + 0x7fffu + ((u >> 16) & 1u)) >> 16);
}
__device__ __forceinline__ u16 f2bf_hw(float f) {
    union { __bf16 b; u16 u; } c;
    c.b = (__bf16)f;
    return c.u;
}
__device__ __forceinline__ void split8(float4 a0, float4 a1, short8& hi, short8& lo) {
    float x8[8] = {a0.x, a0.y, a0.z, a0.w, a1.x, a1.y, a1.z, a1.w};
#pragma unroll
    for (int j = 0; j < 8; ++j) {
        u16 hh = f2bf_hw(x8[j]);
        hi[j] = (short)hh;
        lo[j] = (short)f2bf_hw(x8[j] - bf2f(hh));
    }
}

// Skewed row offset for 36-float rows (+4 floats every 16 rows).
__device__ __forceinline__ int ro(int m) { return m * 36 + ((m >> 4) << 2); }

// Detect input dtype: flag=1 => f32 mode.
__global__ void k_detect(const u16* __restrict__ w, int* __restrict__ flag) {
    __shared__ int cnt;
    if (threadIdx.x == 0) cnt = 0;
    __syncthreads();
    int bad = 0;
    for (int i = threadIdx.x; i < 8192; i += 256) {
        float v = bf2f(w[i]);
        if (!(fabsf(v) <= 1e3f)) bad++;
    }
    if (bad) atomicAdd(&cnt, bad);
    __syncthreads();
    if (threadIdx.x == 0) flag[0] = (cnt > 64) ? 1 : 0;
}

// Transpose the 4 weight matrices into ws as bf16 WT[n][k] (hi; lo in f32 mode).
__global__ __launch_bounds__(256) void k_wt(
    const void* __restrict__ w0, const void* __restrict__ w1,
    const void* __restrict__ w2, const void* __restrict__ w3,
    void* __restrict__ ws, const int* __restrict__ flag) {
    const int f32m = flag[0];
    const int p = blockIdx.x >> 4;
    const int tile = blockIdx.x & 15;
    const int ko = (tile >> 2) << 6;
    const int no = (tile & 3) << 6;
    const void* W = (p == 0) ? w0 : (p == 1) ? w1 : (p == 2) ? w2 : w3;
    u16* hi = (u16*)((char*)ws + 512) + (size_t)p * 65536;
    u16* lo = hi + 4 * 65536;

    __shared__ __align__(16) char tbuf[64 * 65 * 4];
    const int t = threadIdx.x;
    const int tq = t >> 6;
    const int tc = t & 63;

    if (f32m) {
        float (*tl)[65] = (float (*)[65])tbuf;
#pragma unroll
        for (int rr = 0; rr < 16; ++rr) {
            int kk = tq + (rr << 2);
            tl[kk][tc] = ((const float*)W)[(size_t)(ko + kk) * 256 + no + tc];
        }
        __syncthreads();
#pragma unroll
        for (int rr = 0; rr < 16; ++rr) {
            int nn = tq + (rr << 2);
            float x = tl[tc][nn];
            u16 h = f2bf(x);
            size_t o = (size_t)(no + nn) * 256 + ko + tc;
            hi[o] = h;
            lo[o] = f2bf(x - bf2f(h));
        }
    } else {
        u16 (*tl)[65] = (u16 (*)[65])tbuf;
#pragma unroll
        for (int rr = 0; rr < 16; ++rr) {
            int kk = tq + (rr << 2);
            tl[kk][tc] = ((const u16*)W)[(size_t)(ko + kk) * 256 + no + tc];
        }
        __syncthreads();
#pragma unroll
        for (int rr = 0; rr < 16; ++rr) {
            int nn = tq + (rr << 2);
            hi[(size_t)(no + nn) * 256 + ko + tc] = tl[tc][nn];
        }
    }
}

// ---------------------------------------------------------------------------
// k_proj: pure QKV projection. One block per (b,s), grid 1024, 4 waves; wave
// w owns rows [16w,16w+16) x ALL 256 cols x 3 tensors. A-fragments loaded
// ONCE per tensor (reused across 8 col-groups -> 8x load amortization vs the
// fused kernel). Output f32 to ws (bit-identical values to the old LDS path).
// ---------------------------------------------------------------------------
template <bool F32>
__global__ __launch_bounds__(256) void k_proj(
    const void* __restrict__ qv, const void* __restrict__ kv, const void* __restrict__ vv,
    const void* __restrict__ bQv, const void* __restrict__ bKv, const void* __restrict__ bVv,
    void* __restrict__ ws, const int* __restrict__ flag)
{
    if ((flag[0] != 0) != F32) return;

    const int t = threadIdx.x;
    const int wv_ = t >> 6, lane = t & 63, li = lane & 15, lg = lane >> 4;
    const int bs = blockIdx.x;
    const u16* wt = (const u16*)((const char*)ws + 512);
    float* xo = (float*)((char*)ws + XQ_OFF);
    const size_t arow = ((size_t)bs * 64 + wv_ * 16 + li) * 256;
    const int orow0 = wv_ * 16 + lg * 4;

    for (int p = 0; p < 3; ++p) {
        const void* Xp = (p == 0) ? qv : (p == 1) ? kv : vv;
        const void* bp = (p == 0) ? bQv : (p == 1) ? bKv : bVv;
        const u16* wtp = wt + (size_t)p * 65536;
        float* xop = xo + (size_t)p * 16777216 + (size_t)bs * 16384;

        // Hoisted A fragments (reused by all 8 col-groups).
        short8 AH[8], AL[8];
        if constexpr (F32) {
            const float* xp0 = (const float*)Xp + arow + lg * 8;
            float4 X0[8], X1[8];
#pragma unroll
            for (int ks = 0; ks < 8; ++ks) {
                X0[ks] = *(const float4*)(xp0 + ks * 32);
                X1[ks] = *(const float4*)(xp0 + ks * 32 + 4);
            }
#pragma unroll
            for (int ks = 0; ks < 8; ++ks) split8(X0[ks], X1[ks], AH[ks], AL[ks]);
        } else {
#pragma unroll
            for (int ks = 0; ks < 8; ++ks)
                AH[ks] = *(const short8*)((const u16*)Xp + arow + ks * 32 + lg * 8);
        }

#pragma unroll
        for (int cg = 0; cg < 8; ++cg) {
            const u16* b0p = wtp + (size_t)(cg * 32 + li) * 256;
            const u16* b1p = b0p + 4096;      // +16 cols
            float bv0, bv1;
            if constexpr (F32) {
                bv0 = ((const float*)bp)[cg * 32 + li];
                bv1 = ((const float*)bp)[cg * 32 + 16 + li];
            } else {
                bv0 = bf2f(((const u16*)bp)[cg * 32 + li]);
                bv1 = bf2f(((const u16*)bp)[cg * 32 + 16 + li]);
            }
            f32x4 c0 = {bv0, bv0, bv0, bv0};
            f32x4 c1 = {bv1, bv1, bv1, bv1};
#pragma unroll
            for (int ks = 0; ks < 8; ++ks) {
                const int kof = ks * 32 + lg * 8;
                short8 bh0 = *(const short8*)(b0p + kof);
                short8 bh1 = *(const short8*)(b1p + kof);
                c0 = __builtin_amdgcn_mfma_f32_16x16x32_bf16(AH[ks], bh0, c0, 0, 0, 0);
                c1 = __builtin_amdgcn_mfma_f32_16x16x32_bf16(AH[ks], bh1, c1, 0, 0, 0);
                if constexpr (F32) {
                    short8 bl0 = *(const short8*)(b0p + 262144 + kof);
                    short8 bl1 = *(const short8*)(b1p + 262144 + kof);
                    c0 = __builtin_amdgcn_mfma_f32_16x16x32_bf16(AH[ks], bl0, c0, 0, 0, 0);
                    c0 = __builtin_amdgcn_mfma_f32_16x16x32_bf16(AL[ks], bh0, c0, 0, 0, 0);
                    c1 = __builtin_amdgcn_mfma_f32_16x16x32_bf16(AH[ks], bl1, c1, 0, 0, 0);
                    c1 = __builtin_amdgcn_mfma_f32_16x16x32_bf16(AL[ks], bh1, c1, 0, 0, 0);
                }
            }
#pragma unroll
            for (int r = 0; r < 4; ++r) {
                float* orow = xop + (size_t)(orow0 + r) * 256 + cg * 32;
                orow[li] = c0[r];
                orow[16 + li] = c1[r];
            }
        }
    }
}

// ---------------------------------------------------------------------------
// k_attn_ep: epilogue only. One block per (b,s,h); loads Q/K/V head-slices
// (64x32 f32) from ws into the SAME skewed LDS layout, then the verbatim
// scores/softmax/weights-out/PV/attn-out code -> bit-identical output.
// ---------------------------------------------------------------------------
template <bool F32>
__global__ __launch_bounds__(256) void k_attn_ep(
    const void* __restrict__ ws, void* __restrict__ outv, const int* __restrict__ flag)
{
    if ((flag[0] != 0) != F32) return;

    __shared__ float sQ[2320], sK[2320], sV[2320];
    const int t = threadIdx.x;
    const int bs = blockIdx.x >> 3;
    const int h = blockIdx.x & 7;
    const int b = bs >> 7;
    const int s = bs & 127;
    const float* xo = (const float*)((const char*)ws + XQ_OFF);

#pragma unroll
    for (int p = 0; p < 3; ++p) {
        const float* src = xo + (size_t)p * 16777216 + (size_t)bs * 16384 + h * 32;
        float* dst = (p == 0) ? sQ : (p == 1) ? sK : sV;
#pragma unroll
        for (int i = 0; i < 2; ++i) {
            int idx = t + (i << 8);
            int r = idx >> 3;
            int c4 = (idx & 7) << 2;
            *(float4*)&dst[ro(r) + c4] = *(const float4*)(src + (size_t)r * 256 + c4);
        }
    }
    __syncthreads();

    // ---- scores + softmax; thread (n,qq) owns m = qq*16 .. qq*16+15 ----
    const int n = t >> 2;
    const int qq = t & 3;
    float qr[32];
#pragma unroll
    for (int j = 0; j < 8; ++j) {
        float4 f = *(const float4*)&sQ[ro(n) + j * 4];
        qr[j * 4 + 0] = f.x; qr[j * 4 + 1] = f.y;
        qr[j * 4 + 2] = f.z; qr[j * 4 + 3] = f.w;
    }
    const float scale = 0.17677669529663687f;  // 1/sqrt(32)
    float sc[16];
#pragma unroll
    for (int i = 0; i < 16; ++i) {
        int m = qq * 16 + i;
        float d = 0.f;
        const float* kr = &sK[ro(m)];
#pragma unroll
        for (int j = 0; j < 8; ++j) {
            float4 f = *(const float4*)(kr + j * 4);
            d += qr[j * 4 + 0] * f.x + qr[j * 4 + 1] * f.y +
                 qr[j * 4 + 2] * f.z + qr[j * 4 + 3] * f.w;
        }
        sc[i] = d * scale;
    }
    float mx = sc[0];
#pragma unroll
    for (int i = 1; i < 16; ++i) mx = fmaxf(mx, sc[i]);
    mx = fmaxf(mx, __shfl_xor(mx, 1));
    mx = fmaxf(mx, __shfl_xor(mx, 2));
    float sum = 0.f;
#pragma unroll
    for (int i = 0; i < 16; ++i) { sc[i] = __expf(sc[i] - mx); sum += sc[i]; }
    sum += __shfl_xor(sum, 1);
    sum += __shfl_xor(sum, 2);
    const float inv = 1.0f / sum;
#pragma unroll
    for (int i = 0; i < 16; ++i) sc[i] *= inv;

    // weights out
    {
        size_t wbase = ((((size_t)b * HH + h) * SS + s) * NN + n) * NN + (size_t)qq * 16;
        if constexpr (F32) {
            float* wf = (float*)outv + (size_t)OUT0_ELEMS + wbase;
#pragma unroll
            for (int g = 0; g < 4; ++g) {
                float4 f; f.x = sc[g*4]; f.y = sc[g*4+1]; f.z = sc[g*4+2]; f.w = sc[g*4+3];
                *(float4*)(wf + g * 4) = f;
            }
        } else {
            u16* wo = (u16*)outv + (size_t)OUT0_ELEMS + wbase;
            union { u16 u[16]; uint4 v[2]; } wb;
#pragma unroll
            for (int i = 0; i < 16; ++i) wb.u[i] = f2bf(sc[i]);
            *(uint4*)wo = wb.v[0];
            *(uint4*)(wo + 8) = wb.v[1];
        }
    }

    // ---- P @ V ----
    float ao[32];
#pragma unroll
    for (int d = 0; d < 32; ++d) ao[d] = 0.f;
#pragma unroll
    for (int i = 0; i < 16; ++i) {
        int m = qq * 16 + i;
        float w = sc[i];
        const float* vr = &sV[ro(m)];
#pragma unroll
        for (int j = 0; j < 8; ++j) {
            float4 f = *(const float4*)(vr + j * 4);
            ao[j * 4 + 0] += w * f.x; ao[j * 4 + 1] += w * f.y;
            ao[j * 4 + 2] += w * f.z; ao[j * 4 + 3] += w * f.w;
        }
    }
#pragma unroll
    for (int d = 0; d < 32; ++d) {
        ao[d] += __shfl_xor(ao[d], 1);
        ao[d] += __shfl_xor(ao[d], 2);
    }
    {
        size_t abase = ((size_t)bs * NN + n) * DKK + h * DHH + (size_t)qq * 8;
        if constexpr (F32) {
            float* af = (float*)outv + abase;
            float4 f0, f1;
            f0.x = ao[qq*8+0]; f0.y = ao[qq*8+1]; f0.z = ao[qq*8+2]; f0.w = ao[qq*8+3];
            f1.x = ao[qq*8+4]; f1.y = ao[qq*8+5]; f1.z = ao[qq*8+6]; f1.w = ao[qq*8+7];
            *(float4*)af = f0;
            *(float4*)(af + 4) = f1;
        } else {
            union { u16 u[8]; uint4 v; } ob;
#pragma unroll
            for (int u = 0; u < 8; ++u) ob.u[u] = f2bf(ao[qq * 8 + u]);
            *(uint4*)((u16*)outv + abase) = ob.v;
        }
    }
}

// ---------------------------------------------------------------------------
// Fused fallback (round-7 merged kernel, verbatim) — used if ws < WS_FULL.
// ---------------------------------------------------------------------------
template <bool F32>
__global__ __launch_bounds__(256) void k_attn_mfma(
    const void* __restrict__ qv, const void* __restrict__ kv, const void* __restrict__ vv,
    const void* __restrict__ bQv, const void* __restrict__ bKv, const void* __restrict__ bVv,
    const void* __restrict__ ws, void* __restrict__ outv, const int* __restrict__ flag)
{
    if ((flag[0] != 0) != F32) return;

    __shared__ float sQ[2320], sK[2320], sV[2320];

    const int t = threadIdx.x;
    const int wv_ = t >> 6;
    const int lane = t & 63;
    const int li = lane & 15;
    const int lg = lane >> 4;
    const int lid = blockIdx.x;
    const int bs = (lid & 7) + ((lid >> 6) << 3);
    const int h = (lid >> 3) & 7;
    const int b = bs >> 7;
    const int s = bs & 127;

    const u16* wt = (const u16*)((const char*)ws + 512);
    const size_t arow = ((size_t)bs * 64 + wv_ * 16 + li) * 256;
    const u16* b0p = wt + (size_t)(h * 32 + li) * 256;
    const u16* b1p = b0p + 4096;

    f32x4 cQ0, cQ1, cK0, cK1, cV0, cV1;
    {
        float vq0, vq1, vk0, vk1, vv0, vv1;
        if constexpr (F32) {
            vq0 = ((const float*)bQv)[h * 32 + li];
            vq1 = ((const float*)bQv)[h * 32 + 16 + li];
            vk0 = ((const float*)bKv)[h * 32 + li];
            vk1 = ((const float*)bKv)[h * 32 + 16 + li];
            vv0 = ((const float*)bVv)[h * 32 + li];
            vv1 = ((const float*)bVv)[h * 32 + 16 + li];
        } else {
            vq0 = bf2f(((const u16*)bQv)[h * 32 + li]);
            vq1 = bf2f(((const u16*)bQv)[h * 32 + 16 + li]);
            vk0 = bf2f(((const u16*)bKv)[h * 32 + li]);
            vk1 = bf2f(((const u16*)bKv)[h * 32 + 16 + li]);
            vv0 = bf2f(((const u16*)bVv)[h * 32 + li]);
            vv1 = bf2f(((const u16*)bVv)[h * 32 + 16 + li]);
        }
        cQ0 = f32x4{vq0, vq0, vq0, vq0}; cQ1 = f32x4{vq1, vq1, vq1, vq1};
        cK0 = f32x4{vk0, vk0, vk0, vk0}; cK1 = f32x4{vk1, vk1, vk1, vk1};
        cV0 = f32x4{vv0, vv0, vv0, vv0}; cV1 = f32x4{vv1, vv1, vv1, vv1};
    }

    if constexpr (F32) {
        const float* xq = (const float*)qv + arow + lg * 8;
        const float* xk = (const float*)kv + arow + lg * 8;
        const float* xv = (const float*)vv + arow + lg * 8;
#pragma unroll
        for (int ks = 0; ks < 8; ++ks) {
            const int kof = ks * 32 + lg * 8;
            float4 q0 = *(const float4*)(xq + ks * 32);
            float4 q1 = *(const float4*)(xq + ks * 32 + 4);
            float4 k0 = *(const float4*)(xk + ks * 32);
            float4 k1 = *(const float4*)(xk + ks * 32 + 4);
            float4 v0 = *(const float4*)(xv + ks * 32);
            float4 v1 = *(const float4*)(xv + ks * 32 + 4);
            short8 bqh0 = *(const short8*)(b0p + kof);
            short8 bqh1 = *(const short8*)(b1p + kof);
            short8 bql0 = *(const short8*)(b0p + 262144 + kof);
            short8 bql1 = *(const short8*)(b1p + 262144 + kof);
            short8 bkh0 = *(const short8*)(b0p + 65536 + kof);
            short8 bkh1 = *(const short8*)(b1p + 65536 + kof);
            short8 bkl0 = *(const short8*)(b0p + 327680 + kof);
            short8 bkl1 = *(const short8*)(b1p + 327680 + kof);
            short8 bvh0 = *(const short8*)(b0p + 131072 + kof);
            short8 bvh1 = *(const short8*)(b1p + 131072 + kof);
            short8 bvl0 = *(const short8*)(b0p + 393216 + kof);
            short8 bvl1 = *(const short8*)(b1p + 393216 + kof);
            short8 aqh, aql, akh, akl, avh, avl;
            split8(q0, q1, aqh, aql);
            split8(k0, k1, akh, akl);
            split8(v0, v1, avh, avl);
            cQ0 = __builtin_amdgcn_mfma_f32_16x16x32_bf16(aqh, bqh0, cQ0, 0, 0, 0);
            cK0 = __builtin_amdgcn_mfma_f32_16x16x32_bf16(akh, bkh0, cK0, 0, 0, 0);
            cV0 = __builtin_amdgcn_mfma_f32_16x16x32_bf16(avh, bvh0, cV0, 0, 0, 0);
            cQ1 = __builtin_amdgcn_mfma_f32_16x16x32_bf16(aqh, bqh1, cQ1, 0, 0, 0);
            cK1 = __builtin_amdgcn_mfma_f32_16x16x32_bf16(akh, bkh1, cK1, 0, 0, 0);
            cV1 = __builtin_amdgcn_mfma_f32_16x16x32_bf16(avh, bvh1, cV1, 0, 0, 0);
            cQ0 = __builtin_amdgcn_mfma_f32_16x16x32_bf16(aqh, bql0, cQ0, 0, 0, 0);
            cK0 = __builtin_amdgcn_mfma_f32_16x16x32_bf16(akh, bkl0, cK0, 0, 0, 0);
            cV0 = __builtin_amdgcn_mfma_f32_16x16x32_bf16(avh, bvl0, cV0, 0, 0, 0);
            cQ0 = __builtin_amdgcn_mfma_f32_16x16x32_bf16(aql, bqh0, cQ0, 0, 0, 0);
            cK0 = __builtin_amdgcn_mfma_f32_16x16x32_bf16(akl, bkh0, cK0, 0, 0, 0);
            cV0 = __builtin_amdgcn_mfma_f32_16x16x32_bf16(avl, bvh0, cV0, 0, 0, 0);
            cQ1 = __builtin_amdgcn_mfma_f32_16x16x32_bf16(aqh, bql1, cQ1, 0, 0, 0);
            cK1 = __builtin_amdgcn_mfma_f32_16x16x32_bf16(akh, bkl1, cK1, 0, 0, 0);
            cV1 = __builtin_amdgcn_mfma_f32_16x16x32_bf16(avh, bvl1, cV1, 0, 0, 0);
            cQ1 = __builtin_amdgcn_mfma_f32_16x16x32_bf16(aql, bqh1, cQ1, 0, 0, 0);
            cK1 = __builtin_amdgcn_mfma_f32_16x16x32_bf16(akl, bkh1, cK1, 0, 0, 0);
            cV1 = __builtin_amdgcn_mfma_f32_16x16x32_bf16(avl, bvh1, cV1, 0, 0, 0);
        }
    } else {
        const u16* xq = (const u16*)qv + arow;
        const u16* xk = (const u16*)kv + arow;
        const u16* xv = (const u16*)vv + arow;
#pragma unroll
        for (int ks = 0; ks < 8; ++ks) {
            const int kof = ks * 32 + lg * 8;
            short8 aq = *(const short8*)(xq + kof);
            short8 ak = *(const short8*)(xk + kof);
            short8 av = *(const short8*)(xv + kof);
            short8 bq0 = *(const short8*)(b0p + kof);
            short8 bq1 = *(const short8*)(b1p + kof);
            short8 bk0 = *(const short8*)(b0p + 65536 + kof);
            short8 bk1 = *(const short8*)(b1p + 65536 + kof);
            short8 bv0 = *(const short8*)(b0p + 131072 + kof);
            short8 bv1 = *(const short8*)(b1p + 131072 + kof);
            cQ0 = __builtin_amdgcn_mfma_f32_16x16x32_bf16(aq, bq0, cQ0, 0, 0, 0);
            cK0 = __builtin_amdgcn_mfma_f32_16x16x32_bf16(ak, bk0, cK0, 0, 0, 0);
            cV0 = __builtin_amdgcn_mfma_f32_16x16x32_bf16(av, bv0, cV0, 0, 0, 0);
            cQ1 = __builtin_amdgcn_mfma_f32_16x16x32_bf16(aq, bq1, cQ1, 0, 0, 0);
            cK1 = __builtin_amdgcn_mfma_f32_16x16x32_bf16(ak, bk1, cK1, 0, 0, 0);
            cV1 = __builtin_amdgcn_mfma_f32_16x16x32_bf16(av, bv1, cV1, 0, 0, 0);
        }
    }

    {
        const int row0 = wv_ * 16 + lg * 4;
#pragma unroll
        for (int r = 0; r < 4; ++r) {
            int o = ro(row0 + r);
            sQ[o + li] = cQ0[r]; sQ[o + 16 + li] = cQ1[r];
            sK[o + li] = cK0[r]; sK[o + 16 + li] = cK1[r];
            sV[o + li] = cV0[r]; sV[o + 16 + li] = cV1[r];
        }
    }
    __syncthreads();

    const int n = t >> 2;
    const int qq = t & 3;
    float qr[32];
#pragma unroll
    for (int j = 0; j < 8; ++j) {
        float4 f = *(const float4*)&sQ[ro(n) + j * 4];
        qr[j * 4 + 0] = f.x; qr[j * 4 + 1] = f.y;
        qr[j * 4 + 2] = f.z; qr[j * 4 + 3] = f.w;
    }
    const float scale = 0.17677669529663687f;
    float sc[16];
#pragma unroll
    for (int i = 0; i < 16; ++i) {
        int m = qq * 16 + i;
        float d = 0.f;
        const float* kr = &sK[ro(m)];
#pragma unroll
        for (int j = 0; j < 8; ++j) {
            float4 f = *(const float4*)(kr + j * 4);
            d += qr[j * 4 + 0] * f.x + qr[j * 4 + 1] * f.y +
                 qr[j * 4 + 2] * f.z + qr[j * 4 + 3] * f.w;
        }
        sc[i] = d * scale;
    }
    float mx = sc[0];
#pragma unroll
    for (int i = 1; i < 16; ++i) mx = fmaxf(mx, sc[i]);
    mx = fmaxf(mx, __shfl_xor(mx, 1));
    mx = fmaxf(mx, __shfl_xor(mx, 2));
    float sum = 0.f;
#pragma unroll
    for (int i = 0; i < 16; ++i) { sc[i] = __expf(sc[i] - mx); sum += sc[i]; }
    sum += __shfl_xor(sum, 1);
    sum += __shfl_xor(sum, 2);
    const float inv = 1.0f / sum;
#pragma unroll
    for (int i = 0; i < 16; ++i) sc[i] *= inv;

    {
        size_t wbase = ((((size_t)b * HH + h) * SS + s) * NN + n) * NN + (size_t)qq * 16;
        if constexpr (F32) {
            float* wf = (float*)outv + (size_t)OUT0_ELEMS + wbase;
#pragma unroll
            for (int g = 0; g < 4; ++g) {
                float4 f; f.x = sc[g*4]; f.y = sc[g*4+1]; f.z = sc[g*4+2]; f.w = sc[g*4+3];
                *(float4*)(wf + g * 4) = f;
            }
        } else {
            u16* wo = (u16*)outv + (size_t)OUT0_ELEMS + wbase;
            union { u16 u[16]; uint4 v[2]; } wb;
#pragma unroll
            for (int i = 0; i < 16; ++i) wb.u[i] = f2bf(sc[i]);
            *(uint4*)wo = wb.v[0];
            *(uint4*)(wo + 8) = wb.v[1];
        }
    }

    float ao[32];
#pragma unroll
    for (int d = 0; d < 32; ++d) ao[d] = 0.f;
#pragma unroll
    for (int i = 0; i < 16; ++i) {
        int m = qq * 16 + i;
        float w = sc[i];
        const float* vr = &sV[ro(m)];
#pragma unroll
        for (int j = 0; j < 8; ++j) {
            float4 f = *(const float4*)(vr + j * 4);
            ao[j * 4 + 0] += w * f.x; ao[j * 4 + 1] += w * f.y;
            ao[j * 4 + 2] += w * f.z; ao[j * 4 + 3] += w * f.w;
        }
    }
#pragma unroll
    for (int d = 0; d < 32; ++d) {
        ao[d] += __shfl_xor(ao[d], 1);
        ao[d] += __shfl_xor(ao[d], 2);
    }
    {
        size_t abase = ((size_t)bs * NN + n) * DKK + h * DHH + (size_t)qq * 8;
        if constexpr (F32) {
            float* af = (float*)outv + abase;
            float4 f0, f1;
            f0.x = ao[qq*8+0]; f0.y = ao[qq*8+1]; f0.z = ao[qq*8+2]; f0.w = ao[qq*8+3];
            f1.x = ao[qq*8+4]; f1.y = ao[qq*8+5]; f1.z = ao[qq*8+6]; f1.w = ao[qq*8+7];
            *(float4*)af = f0;
            *(float4*)(af + 4) = f1;
        } else {
            union { u16 u[8]; uint4 v; } ob;
#pragma unroll
            for (int u = 0; u < 8; ++u) ob.u[u] = f2bf(ao[qq * 8 + u]);
            *(uint4*)((u16*)outv + abase) = ob.v;
        }
    }
}

// ---------------------------------------------------------------------------
// MFMA out-projection with 2-column ILP (2 independent chains per iteration;
// per-chain op order unchanged -> bit-identical).
// ---------------------------------------------------------------------------
template <bool F32>
__global__ __launch_bounds__(256) void k_outproj_mfma(
    const void* __restrict__ ws, const void* __restrict__ bOv,
    void* __restrict__ outv, const int* __restrict__ flag)
{
    if ((flag[0] != 0) != F32) return;

    const int t = threadIdx.x;
    const int wv_ = t >> 6, lane = t & 63, li = lane & 15, lg = lane >> 4;
    const size_t base = (size_t)blockIdx.x * (NN * DKK);
    const u16* wt = (const u16*)((const char*)ws + 512) + (size_t)3 * 65536;
    const u16* wtl = wt + 4 * 65536;

    short8 a[8];
    const size_t arow = base + (size_t)(wv_ * 16 + li) * 256;
    if constexpr (F32) {
        float4 X0[8], X1[8];
        const float* xp0 = (const float*)outv + arow + lg * 8;
#pragma unroll
        for (int ks = 0; ks < 8; ++ks) {
            X0[ks] = *(const float4*)(xp0 + ks * 32);
            X1[ks] = *(const float4*)(xp0 + ks * 32 + 4);
        }
#pragma unroll
        for (int ks = 0; ks < 8; ++ks) {
            float x8[8] = {X0[ks].x, X0[ks].y, X0[ks].z, X0[ks].w,
                           X1[ks].x, X1[ks].y, X1[ks].z, X1[ks].w};
#pragma unroll
            for (int j = 0; j < 8; ++j) a[ks][j] = (short)f2bf_hw(x8[j]);
        }
    } else {
#pragma unroll
        for (int ks = 0; ks < 8; ++ks) {
            const int kof = ks * 32 + lg * 8;
            a[ks] = *(const short8*)((const u16*)outv + arow + kof);
        }
    }

    for (int nt = 0; nt < 16; nt += 2) {
        const int colA = nt * 16 + li;
        const int colB = colA + 16;
        float bvA, bvB;
        if constexpr (F32) {
            bvA = ((const float*)bOv)[colA];
            bvB = ((const float*)bOv)[colB];
        } else {
            bvA = bf2f(((const u16*)bOv)[colA]);
            bvB = bf2f(((const u16*)bOv)[colB]);
        }
        f32x4 cA = {bvA, bvA, bvA, bvA};
        f32x4 cB = {bvB, bvB, bvB, bvB};
#pragma unroll
        for (int ks = 0; ks < 8; ++ks) {
            const int kof = ks * 32 + lg * 8;
            short8 bhA = *(const short8*)(wt + (size_t)colA * 256 + kof);
            short8 bhB = *(const short8*)(wt + (size_t)colB * 256 + kof);
            cA = __builtin_amdgcn_mfma_f32_16x16x32_bf16(a[ks], bhA, cA, 0, 0, 0);
            cB = __builtin_amdgcn_mfma_f32_16x16x32_bf16(a[ks], bhB, cB, 0, 0, 0);
            if constexpr (F32) {
                short8 blA = *(const short8*)(wtl + (size_t)colA * 256 + kof);
                short8 blB = *(const short8*)(wtl + (size_t)colB * 256 + kof);
                cA = __builtin_amdgcn_mfma_f32_16x16x32_bf16(a[ks], blA, cA, 0, 0, 0);
                cB = __builtin_amdgcn_mfma_f32_16x16x32_bf16(a[ks], blB, cB, 0, 0, 0);
            }
        }
#pragma unroll
        for (int r = 0; r < 4; ++r) {
            size_t offA = base + (size_t)(wv_ * 16 + lg * 4 + r) * 256 + colA;
            if constexpr (F32) {
                ((float*)outv)[offA] = cA[r];
                ((float*)outv)[offA + 16] = cB[r];
            } else {
                ((u16*)outv)[offA] = f2bf(cA[r]);
                ((u16*)outv)[offA + 16] = f2bf(cB[r]);
            }
        }
    }
}

extern "C" void kernel_launch(void* const* d_in, const int* in_sizes, int n_in,
                              void* d_out, int out_size, void* d_ws, size_t ws_size,
                              hipStream_t stream) {
    (void)in_sizes; (void)n_in; (void)out_size;
    int* flag = (int*)d_ws;

    k_detect<<<1, 256, 0, stream>>>((const u16*)d_in[3], flag);

    if (ws_size >= WS_FULL) {
        k_wt<<<64, 256, 0, stream>>>(d_in[3], d_in[5], d_in[7], d_in[9], d_ws, flag);

        k_proj<false><<<BB * SS, 256, 0, stream>>>(
            d_in[0], d_in[1], d_in[2], d_in[4], d_in[6], d_in[8], d_ws, flag);
        k_proj<true><<<BB * SS, 256, 0, stream>>>(
            d_in[0], d_in[1], d_in[2], d_in[4], d_in[6], d_in[8], d_ws, flag);

        k_attn_ep<false><<<BB * SS * HH, 256, 0, stream>>>(d_ws, d_out, flag);
        k_attn_ep<true><<<BB * SS * HH, 256, 0, stream>>>(d_ws, d_out, flag);

        k_outproj_mfma<false><<<BB * SS, 256, 0, stream>>>(d_ws, d_in[10], d_out, flag);
        k_outproj_mfma<true><<<BB * SS, 256, 0, stream>>>(d_ws, d_in[10], d_out, flag);
    } else if (ws_size >= WS_WT) {
        k_wt<<<64, 256, 0, stream>>>(d_in[3], d_in[5], d_in[7], d_in[9], d_ws, flag);

        k_attn_mfma<false><<<BB * SS * HH, 256, 0, stream>>>(
            d_in[0], d_in[1], d_in[2], d_in[4], d_in[6], d_in[8],
            d_ws, d_out, flag);
        k_attn_mfma<true><<<BB * SS * HH, 256, 0, stream>>>(
            d_in[0], d_in[1], d_in[2], d_in[4], d_in[6], d_in[8],
            d_ws, d_out, flag);

        k_outproj_mfma<false><<<BB * SS, 256, 0, stream>>>(d_ws, d_in[10], d_out, flag);
        k_outproj_mfma<true><<<BB * SS, 256, 0, stream>>>(d_ws, d_in[10], d_out, flag);
    }
}

// Round 9
// 659.136 us; speedup vs baseline: 1.5935x; 1.5935x over previous
//
#include <hip/hip_runtime.h>

#define BB 8
#define SS 128
#define NN 64
#define DKK 256
#define HH 8
#define DHH 32
#define OUT0_ELEMS 16777216   // B*S*N*DK
// weights elems: B*H*S*N*N = 33554432

typedef unsigned short u16;
typedef __attribute__((ext_vector_type(8))) short short8;   // 8 bf16 (4 VGPRs)
typedef __attribute__((ext_vector_type(4))) float f32x4;    // MFMA C/D frag

// ws layout: [0,512) flag; [512, 512+1MiB) weight FRAGMENTS hi(4x128K)+lo(4x128K)
// in fragment-major order (see k_wt); [2MiB, 2MiB+192MiB) projected QKV f32.
#define WS_WT 1049088ull
#define XQ_OFF 2097152ull
#define WS_FULL 203423744ull   // 2MiB + 3*64MiB

__device__ __forceinline__ float bf2f(u16 u) {
    union { unsigned int ui; float f; } c;
    c.ui = ((unsigned int)u) << 16;
    return c.f;
}
__device__ __forceinline__ u16 f2bf(float f) {
    union { float f; unsigned int u; } c;
    c.f = f;
    unsigned int u = c.u;
    return (u16)((u + 0x7fffu + ((u >> 16) & 1u)) >> 16);
}
__device__ __forceinline__ u16 f2bf_hw(float f) {
    union { __bf16 b; u16 u; } c;
    c.b = (__bf16)f;
    return c.u;
}
__device__ __forceinline__ void split8(float4 a0, float4 a1, short8& hi, short8& lo) {
    float x8[8] = {a0.x, a0.y, a0.z, a0.w, a1.x, a1.y, a1.z, a1.w};
#pragma unroll
    for (int j = 0; j < 8; ++j) {
        u16 hh = f2bf_hw(x8[j]);
        hi[j] = (short)hh;
        lo[j] = (short)f2bf_hw(x8[j] - bf2f(hh));
    }
}

// Skewed row offset for 36-float rows (+4 floats every 16 rows).
__device__ __forceinline__ int ro(int m) { return m * 36 + ((m >> 4) << 2); }

// Detect input dtype: flag=1 => f32 mode.
__global__ void k_detect(const u16* __restrict__ w, int* __restrict__ flag) {
    __shared__ int cnt;
    if (threadIdx.x == 0) cnt = 0;
    __syncthreads();
    int bad = 0;
    for (int i = threadIdx.x; i < 8192; i += 256) {
        float v = bf2f(w[i]);
        if (!(fabsf(v) <= 1e3f)) bad++;
    }
    if (bad) atomicAdd(&cnt, bad);
    __syncthreads();
    if (threadIdx.x == 0) flag[0] = (cnt > 64) ? 1 : 0;
}

// Fragment offset (u16 units) within a 65536-u16 weight plane.
// QKV (mat<3):  n -> cg=n>>5, f=(n>>4)&1, li=n&15 ; k -> ks=k>>5, lg=(k>>3)&3, j=k&7
//   off = ((cg*8+ks)*2+f)*512 + (lg*16+li)*8 + j     (lane = lg*16+li)
// WO  (mat==3): n -> nt=n>>4, li=n&15
//   off = (nt*8+ks)*512 + (lg*16+li)*8 + j
// A wave's B-fragment load is then 64 lanes x 16B CONTIGUOUS (1KB burst) --
// the old WT[n][k] layout made every B-load a 32-cache-line gather (lanes
// 512B apart), which saturated VMEM line-request throughput (r8: k_proj
// 587us with ALL pipes <6% busy).
__device__ __forceinline__ size_t frag_off(int mat, int n, int k) {
    int li = n & 15, lg = (k >> 3) & 3, ks = k >> 5, j = k & 7;
    if (mat == 3) {
        int nt = n >> 4;
        return (size_t)(nt * 8 + ks) * 512 + (lg * 16 + li) * 8 + j;
    }
    int cg = n >> 5, f = (n >> 4) & 1;
    return (size_t)((cg * 8 + ks) * 2 + f) * 512 + (lg * 16 + li) * 8 + j;
}

// Repack the 4 weight matrices into fragment-major bf16 (hi; +lo in f32 mode).
__global__ __launch_bounds__(256) void k_wt(
    const void* __restrict__ w0, const void* __restrict__ w1,
    const void* __restrict__ w2, const void* __restrict__ w3,
    void* __restrict__ ws, const int* __restrict__ flag) {
    const int f32m = flag[0];
    const int p = blockIdx.x >> 4;
    const int tile = blockIdx.x & 15;
    const int ko = (tile >> 2) << 6;
    const int no = (tile & 3) << 6;
    const void* W = (p == 0) ? w0 : (p == 1) ? w1 : (p == 2) ? w2 : w3;
    u16* hi = (u16*)((char*)ws + 512) + (size_t)p * 65536;
    u16* lo = hi + 4 * 65536;

    __shared__ __align__(16) char tbuf[64 * 65 * 4];
    const int t = threadIdx.x;
    const int tq = t >> 6;
    const int tc = t & 63;

    if (f32m) {
        float (*tl)[65] = (float (*)[65])tbuf;
#pragma unroll
        for (int rr = 0; rr < 16; ++rr) {
            int kk = tq + (rr << 2);
            tl[kk][tc] = ((const float*)W)[(size_t)(ko + kk) * 256 + no + tc];
        }
        __syncthreads();
#pragma unroll
        for (int rr = 0; rr < 16; ++rr) {
            int nn = tq + (rr << 2);
            float x = tl[tc][nn];          // = W[ko+tc][no+nn]
            u16 h = f2bf(x);
            size_t o = frag_off(p, no + nn, ko + tc);
            hi[o] = h;
            lo[o] = f2bf(x - bf2f(h));
        }
    } else {
        u16 (*tl)[65] = (u16 (*)[65])tbuf;
#pragma unroll
        for (int rr = 0; rr < 16; ++rr) {
            int kk = tq + (rr << 2);
            tl[kk][tc] = ((const u16*)W)[(size_t)(ko + kk) * 256 + no + tc];
        }
        __syncthreads();
#pragma unroll
        for (int rr = 0; rr < 16; ++rr) {
            int nn = tq + (rr << 2);
            hi[frag_off(p, no + nn, ko + tc)] = tl[tc][nn];
        }
    }
}

// ---------------------------------------------------------------------------
// k_proj: pure QKV projection. One block per (b,s), 4 waves; wave w owns rows
// [16w,16w+16) x all 256 cols x 3 tensors. A-fragments loaded once per tensor;
// B-fragments are coalesced 1KB bursts from the fragment-major planes.
// ---------------------------------------------------------------------------
template <bool F32>
__global__ __launch_bounds__(256) void k_proj(
    const void* __restrict__ qv, const void* __restrict__ kv, const void* __restrict__ vv,
    const void* __restrict__ bQv, const void* __restrict__ bKv, const void* __restrict__ bVv,
    void* __restrict__ ws, const int* __restrict__ flag)
{
    if ((flag[0] != 0) != F32) return;

    const int t = threadIdx.x;
    const int wv_ = t >> 6, lane = t & 63, li = lane & 15, lg = lane >> 4;
    const int bs = blockIdx.x;
    const u16* wt = (const u16*)((const char*)ws + 512);
    float* xo = (float*)((char*)ws + XQ_OFF);
    const size_t arow = ((size_t)bs * 64 + wv_ * 16 + li) * 256;
    const int orow0 = wv_ * 16 + lg * 4;

    for (int p = 0; p < 3; ++p) {
        const void* Xp = (p == 0) ? qv : (p == 1) ? kv : vv;
        const void* bp = (p == 0) ? bQv : (p == 1) ? bKv : bVv;
        const u16* wtp = wt + (size_t)p * 65536 + lane * 8;   // frag-major base
        float* xop = xo + (size_t)p * 16777216 + (size_t)bs * 16384;

        // Hoisted A fragments (reused by all 8 col-groups).
        short8 AH[8], AL[8];
        if constexpr (F32) {
            const float* xp0 = (const float*)Xp + arow + lg * 8;
            float4 X0[8], X1[8];
#pragma unroll
            for (int ks = 0; ks < 8; ++ks) {
                X0[ks] = *(const float4*)(xp0 + ks * 32);
                X1[ks] = *(const float4*)(xp0 + ks * 32 + 4);
            }
#pragma unroll
            for (int ks = 0; ks < 8; ++ks) split8(X0[ks], X1[ks], AH[ks], AL[ks]);
        } else {
#pragma unroll
            for (int ks = 0; ks < 8; ++ks)
                AH[ks] = *(const short8*)((const u16*)Xp + arow + ks * 32 + lg * 8);
        }

#pragma unroll
        for (int cg = 0; cg < 8; ++cg) {
            const u16* cgb = wtp + cg * 8192;
            float bv0, bv1;
            if constexpr (F32) {
                bv0 = ((const float*)bp)[cg * 32 + li];
                bv1 = ((const float*)bp)[cg * 32 + 16 + li];
            } else {
                bv0 = bf2f(((const u16*)bp)[cg * 32 + li]);
                bv1 = bf2f(((const u16*)bp)[cg * 32 + 16 + li]);
            }
            f32x4 c0 = {bv0, bv0, bv0, bv0};
            f32x4 c1 = {bv1, bv1, bv1, bv1};
#pragma unroll
            for (int ks = 0; ks < 8; ++ks) {
                const u16* bb = cgb + ks * 1024;
                short8 bh0 = *(const short8*)(bb);
                short8 bh1 = *(const short8*)(bb + 512);
                c0 = __builtin_amdgcn_mfma_f32_16x16x32_bf16(AH[ks], bh0, c0, 0, 0, 0);
                c1 = __builtin_amdgcn_mfma_f32_16x16x32_bf16(AH[ks], bh1, c1, 0, 0, 0);
                if constexpr (F32) {
                    short8 bl0 = *(const short8*)(bb + 262144);
                    short8 bl1 = *(const short8*)(bb + 262144 + 512);
                    c0 = __builtin_amdgcn_mfma_f32_16x16x32_bf16(AH[ks], bl0, c0, 0, 0, 0);
                    c0 = __builtin_amdgcn_mfma_f32_16x16x32_bf16(AL[ks], bh0, c0, 0, 0, 0);
                    c1 = __builtin_amdgcn_mfma_f32_16x16x32_bf16(AH[ks], bl1, c1, 0, 0, 0);
                    c1 = __builtin_amdgcn_mfma_f32_16x16x32_bf16(AL[ks], bh1, c1, 0, 0, 0);
                }
            }
#pragma unroll
            for (int r = 0; r < 4; ++r) {
                float* orow = xop + (size_t)(orow0 + r) * 256 + cg * 32;
                orow[li] = c0[r];
                orow[16 + li] = c1[r];
            }
        }
    }
}

// ---------------------------------------------------------------------------
// k_attn_ep: epilogue only. One block per (b,s,h); loads Q/K/V head-slices
// (64x32 f32) from ws into the skewed LDS layout, then the verbatim
// scores/softmax/weights-out/PV/attn-out code -> bit-identical output.
// ---------------------------------------------------------------------------
template <bool F32>
__global__ __launch_bounds__(256) void k_attn_ep(
    const void* __restrict__ ws, void* __restrict__ outv, const int* __restrict__ flag)
{
    if ((flag[0] != 0) != F32) return;

    __shared__ float sQ[2320], sK[2320], sV[2320];
    const int t = threadIdx.x;
    const int bs = blockIdx.x >> 3;
    const int h = blockIdx.x & 7;
    const int b = bs >> 7;
    const int s = bs & 127;
    const float* xo = (const float*)((const char*)ws + XQ_OFF);

#pragma unroll
    for (int p = 0; p < 3; ++p) {
        const float* src = xo + (size_t)p * 16777216 + (size_t)bs * 16384 + h * 32;
        float* dst = (p == 0) ? sQ : (p == 1) ? sK : sV;
#pragma unroll
        for (int i = 0; i < 2; ++i) {
            int idx = t + (i << 8);
            int r = idx >> 3;
            int c4 = (idx & 7) << 2;
            *(float4*)&dst[ro(r) + c4] = *(const float4*)(src + (size_t)r * 256 + c4);
        }
    }
    __syncthreads();

    // ---- scores + softmax; thread (n,qq) owns m = qq*16 .. qq*16+15 ----
    const int n = t >> 2;
    const int qq = t & 3;
    float qr[32];
#pragma unroll
    for (int j = 0; j < 8; ++j) {
        float4 f = *(const float4*)&sQ[ro(n) + j * 4];
        qr[j * 4 + 0] = f.x; qr[j * 4 + 1] = f.y;
        qr[j * 4 + 2] = f.z; qr[j * 4 + 3] = f.w;
    }
    const float scale = 0.17677669529663687f;  // 1/sqrt(32)
    float sc[16];
#pragma unroll
    for (int i = 0; i < 16; ++i) {
        int m = qq * 16 + i;
        float d = 0.f;
        const float* kr = &sK[ro(m)];
#pragma unroll
        for (int j = 0; j < 8; ++j) {
            float4 f = *(const float4*)(kr + j * 4);
            d += qr[j * 4 + 0] * f.x + qr[j * 4 + 1] * f.y +
                 qr[j * 4 + 2] * f.z + qr[j * 4 + 3] * f.w;
        }
        sc[i] = d * scale;
    }
    float mx = sc[0];
#pragma unroll
    for (int i = 1; i < 16; ++i) mx = fmaxf(mx, sc[i]);
    mx = fmaxf(mx, __shfl_xor(mx, 1));
    mx = fmaxf(mx, __shfl_xor(mx, 2));
    float sum = 0.f;
#pragma unroll
    for (int i = 0; i < 16; ++i) { sc[i] = __expf(sc[i] - mx); sum += sc[i]; }
    sum += __shfl_xor(sum, 1);
    sum += __shfl_xor(sum, 2);
    const float inv = 1.0f / sum;
#pragma unroll
    for (int i = 0; i < 16; ++i) sc[i] *= inv;

    // weights out
    {
        size_t wbase = ((((size_t)b * HH + h) * SS + s) * NN + n) * NN + (size_t)qq * 16;
        if constexpr (F32) {
            float* wf = (float*)outv + (size_t)OUT0_ELEMS + wbase;
#pragma unroll
            for (int g = 0; g < 4; ++g) {
                float4 f; f.x = sc[g*4]; f.y = sc[g*4+1]; f.z = sc[g*4+2]; f.w = sc[g*4+3];
                *(float4*)(wf + g * 4) = f;
            }
        } else {
            u16* wo = (u16*)outv + (size_t)OUT0_ELEMS + wbase;
            union { u16 u[16]; uint4 v[2]; } wb;
#pragma unroll
            for (int i = 0; i < 16; ++i) wb.u[i] = f2bf(sc[i]);
            *(uint4*)wo = wb.v[0];
            *(uint4*)(wo + 8) = wb.v[1];
        }
    }

    // ---- P @ V ----
    float ao[32];
#pragma unroll
    for (int d = 0; d < 32; ++d) ao[d] = 0.f;
#pragma unroll
    for (int i = 0; i < 16; ++i) {
        int m = qq * 16 + i;
        float w = sc[i];
        const float* vr = &sV[ro(m)];
#pragma unroll
        for (int j = 0; j < 8; ++j) {
            float4 f = *(const float4*)(vr + j * 4);
            ao[j * 4 + 0] += w * f.x; ao[j * 4 + 1] += w * f.y;
            ao[j * 4 + 2] += w * f.z; ao[j * 4 + 3] += w * f.w;
        }
    }
#pragma unroll
    for (int d = 0; d < 32; ++d) {
        ao[d] += __shfl_xor(ao[d], 1);
        ao[d] += __shfl_xor(ao[d], 2);
    }
    {
        size_t abase = ((size_t)bs * NN + n) * DKK + h * DHH + (size_t)qq * 8;
        if constexpr (F32) {
            float* af = (float*)outv + abase;
            float4 f0, f1;
            f0.x = ao[qq*8+0]; f0.y = ao[qq*8+1]; f0.z = ao[qq*8+2]; f0.w = ao[qq*8+3];
            f1.x = ao[qq*8+4]; f1.y = ao[qq*8+5]; f1.z = ao[qq*8+6]; f1.w = ao[qq*8+7];
            *(float4*)af = f0;
            *(float4*)(af + 4) = f1;
        } else {
            union { u16 u[8]; uint4 v; } ob;
#pragma unroll
            for (int u = 0; u < 8; ++u) ob.u[u] = f2bf(ao[qq * 8 + u]);
            *(uint4*)((u16*)outv + abase) = ob.v;
        }
    }
}

// ---------------------------------------------------------------------------
// Fused fallback (ws in [WS_WT, WS_FULL)): round-7 merged kernel with B-loads
// updated to the fragment-major layout (same bytes, coalesced).
// ---------------------------------------------------------------------------
template <bool F32>
__global__ __launch_bounds__(256) void k_attn_mfma(
    const void* __restrict__ qv, const void* __restrict__ kv, const void* __restrict__ vv,
    const void* __restrict__ bQv, const void* __restrict__ bKv, const void* __restrict__ bVv,
    const void* __restrict__ ws, void* __restrict__ outv, const int* __restrict__ flag)
{
    if ((flag[0] != 0) != F32) return;

    __shared__ float sQ[2320], sK[2320], sV[2320];

    const int t = threadIdx.x;
    const int wv_ = t >> 6;
    const int lane = t & 63;
    const int li = lane & 15;
    const int lg = lane >> 4;
    const int lid = blockIdx.x;
    const int bs = (lid & 7) + ((lid >> 6) << 3);
    const int h = (lid >> 3) & 7;
    const int b = bs >> 7;
    const int s = bs & 127;

    const u16* wt = (const u16*)((const char*)ws + 512);
    const size_t arow = ((size_t)bs * 64 + wv_ * 16 + li) * 256;
    const u16* fb = wt + h * 8192 + lane * 8;   // frag-major, cg = h

    f32x4 cQ0, cQ1, cK0, cK1, cV0, cV1;
    {
        float vq0, vq1, vk0, vk1, vv0, vv1;
        if constexpr (F32) {
            vq0 = ((const float*)bQv)[h * 32 + li];
            vq1 = ((const float*)bQv)[h * 32 + 16 + li];
            vk0 = ((const float*)bKv)[h * 32 + li];
            vk1 = ((const float*)bKv)[h * 32 + 16 + li];
            vv0 = ((const float*)bVv)[h * 32 + li];
            vv1 = ((const float*)bVv)[h * 32 + 16 + li];
        } else {
            vq0 = bf2f(((const u16*)bQv)[h * 32 + li]);
            vq1 = bf2f(((const u16*)bQv)[h * 32 + 16 + li]);
            vk0 = bf2f(((const u16*)bKv)[h * 32 + li]);
            vk1 = bf2f(((const u16*)bKv)[h * 32 + 16 + li]);
            vv0 = bf2f(((const u16*)bVv)[h * 32 + li]);
            vv1 = bf2f(((const u16*)bVv)[h * 32 + 16 + li]);
        }
        cQ0 = f32x4{vq0, vq0, vq0, vq0}; cQ1 = f32x4{vq1, vq1, vq1, vq1};
        cK0 = f32x4{vk0, vk0, vk0, vk0}; cK1 = f32x4{vk1, vk1, vk1, vk1};
        cV0 = f32x4{vv0, vv0, vv0, vv0}; cV1 = f32x4{vv1, vv1, vv1, vv1};
    }

    if constexpr (F32) {
        const float* xq = (const float*)qv + arow + lg * 8;
        const float* xk = (const float*)kv + arow + lg * 8;
        const float* xv = (const float*)vv + arow + lg * 8;
#pragma unroll
        for (int ks = 0; ks < 8; ++ks) {
            const u16* bb = fb + ks * 1024;
            float4 q0 = *(const float4*)(xq + ks * 32);
            float4 q1 = *(const float4*)(xq + ks * 32 + 4);
            float4 k0 = *(const float4*)(xk + ks * 32);
            float4 k1 = *(const float4*)(xk + ks * 32 + 4);
            float4 v0 = *(const float4*)(xv + ks * 32);
            float4 v1 = *(const float4*)(xv + ks * 32 + 4);
            short8 bqh0 = *(const short8*)(bb);
            short8 bqh1 = *(const short8*)(bb + 512);
            short8 bql0 = *(const short8*)(bb + 262144);
            short8 bql1 = *(const short8*)(bb + 262144 + 512);
            short8 bkh0 = *(const short8*)(bb + 65536);
            short8 bkh1 = *(const short8*)(bb + 65536 + 512);
            short8 bkl0 = *(const short8*)(bb + 327680);
            short8 bkl1 = *(const short8*)(bb + 327680 + 512);
            short8 bvh0 = *(const short8*)(bb + 131072);
            short8 bvh1 = *(const short8*)(bb + 131072 + 512);
            short8 bvl0 = *(const short8*)(bb + 393216);
            short8 bvl1 = *(const short8*)(bb + 393216 + 512);
            short8 aqh, aql, akh, akl, avh, avl;
            split8(q0, q1, aqh, aql);
            split8(k0, k1, akh, akl);
            split8(v0, v1, avh, avl);
            cQ0 = __builtin_amdgcn_mfma_f32_16x16x32_bf16(aqh, bqh0, cQ0, 0, 0, 0);
            cK0 = __builtin_amdgcn_mfma_f32_16x16x32_bf16(akh, bkh0, cK0, 0, 0, 0);
            cV0 = __builtin_amdgcn_mfma_f32_16x16x32_bf16(avh, bvh0, cV0, 0, 0, 0);
            cQ1 = __builtin_amdgcn_mfma_f32_16x16x32_bf16(aqh, bqh1, cQ1, 0, 0, 0);
            cK1 = __builtin_amdgcn_mfma_f32_16x16x32_bf16(akh, bkh1, cK1, 0, 0, 0);
            cV1 = __builtin_amdgcn_mfma_f32_16x16x32_bf16(avh, bvh1, cV1, 0, 0, 0);
            cQ0 = __builtin_amdgcn_mfma_f32_16x16x32_bf16(aqh, bql0, cQ0, 0, 0, 0);
            cK0 = __builtin_amdgcn_mfma_f32_16x16x32_bf16(akh, bkl0, cK0, 0, 0, 0);
            cV0 = __builtin_amdgcn_mfma_f32_16x16x32_bf16(avh, bvl0, cV0, 0, 0, 0);
            cQ0 = __builtin_amdgcn_mfma_f32_16x16x32_bf16(aql, bqh0, cQ0, 0, 0, 0);
            cK0 = __builtin_amdgcn_mfma_f32_16x16x32_bf16(akl, bkh0, cK0, 0, 0, 0);
            cV0 = __builtin_amdgcn_mfma_f32_16x16x32_bf16(avl, bvh0, cV0, 0, 0, 0);
            cQ1 = __builtin_amdgcn_mfma_f32_16x16x32_bf16(aqh, bql1, cQ1, 0, 0, 0);
            cK1 = __builtin_amdgcn_mfma_f32_16x16x32_bf16(akh, bkl1, cK1, 0, 0, 0);
            cV1 = __builtin_amdgcn_mfma_f32_16x16x32_bf16(avh, bvl1, cV1, 0, 0, 0);
            cQ1 = __builtin_amdgcn_mfma_f32_16x16x32_bf16(aql, bqh1, cQ1, 0, 0, 0);
            cK1 = __builtin_amdgcn_mfma_f32_16x16x32_bf16(akl, bkh1, cK1, 0, 0, 0);
            cV1 = __builtin_amdgcn_mfma_f32_16x16x32_bf16(avl, bvh1, cV1, 0, 0, 0);
        }
    } else {
        const u16* xq = (const u16*)qv + arow;
        const u16* xk = (const u16*)kv + arow;
        const u16* xv = (const u16*)vv + arow;
#pragma unroll
        for (int ks = 0; ks < 8; ++ks) {
            const int kof = ks * 32 + lg * 8;
            const u16* bb = fb + ks * 1024;
            short8 aq = *(const short8*)(xq + kof);
            short8 ak = *(const short8*)(xk + kof);
            short8 av = *(const short8*)(xv + kof);
            short8 bq0 = *(const short8*)(bb);
            short8 bq1 = *(const short8*)(bb + 512);
            short8 bk0 = *(const short8*)(bb + 65536);
            short8 bk1 = *(const short8*)(bb + 65536 + 512);
            short8 bv0 = *(const short8*)(bb + 131072);
            short8 bv1 = *(const short8*)(bb + 131072 + 512);
            cQ0 = __builtin_amdgcn_mfma_f32_16x16x32_bf16(aq, bq0, cQ0, 0, 0, 0);
            cK0 = __builtin_amdgcn_mfma_f32_16x16x32_bf16(ak, bk0, cK0, 0, 0, 0);
            cV0 = __builtin_amdgcn_mfma_f32_16x16x32_bf16(av, bv0, cV0, 0, 0, 0);
            cQ1 = __builtin_amdgcn_mfma_f32_16x16x32_bf16(aq, bq1, cQ1, 0, 0, 0);
            cK1 = __builtin_amdgcn_mfma_f32_16x16x32_bf16(ak, bk1, cK1, 0, 0, 0);
            cV1 = __builtin_amdgcn_mfma_f32_16x16x32_bf16(av, bv1, cV1, 0, 0, 0);
        }
    }

    {
        const int row0 = wv_ * 16 + lg * 4;
#pragma unroll
        for (int r = 0; r < 4; ++r) {
            int o = ro(row0 + r);
            sQ[o + li] = cQ0[r]; sQ[o + 16 + li] = cQ1[r];
            sK[o + li] = cK0[r]; sK[o + 16 + li] = cK1[r];
            sV[o + li] = cV0[r]; sV[o + 16 + li] = cV1[r];
        }
    }
    __syncthreads();

    const int n = t >> 2;
    const int qq = t & 3;
    float qr[32];
#pragma unroll
    for (int j = 0; j < 8; ++j) {
        float4 f = *(const float4*)&sQ[ro(n) + j * 4];
        qr[j * 4 + 0] = f.x; qr[j * 4 + 1] = f.y;
        qr[j * 4 + 2] = f.z; qr[j * 4 + 3] = f.w;
    }
    const float scale = 0.17677669529663687f;
    float sc[16];
#pragma unroll
    for (int i = 0; i < 16; ++i) {
        int m = qq * 16 + i;
        float d = 0.f;
        const float* kr = &sK[ro(m)];
#pragma unroll
        for (int j = 0; j < 8; ++j) {
            float4 f = *(const float4*)(kr + j * 4);
            d += qr[j * 4 + 0] * f.x + qr[j * 4 + 1] * f.y +
                 qr[j * 4 + 2] * f.z + qr[j * 4 + 3] * f.w;
        }
        sc[i] = d * scale;
    }
    float mx = sc[0];
#pragma unroll
    for (int i = 1; i < 16; ++i) mx = fmaxf(mx, sc[i]);
    mx = fmaxf(mx, __shfl_xor(mx, 1));
    mx = fmaxf(mx, __shfl_xor(mx, 2));
    float sum = 0.f;
#pragma unroll
    for (int i = 0; i < 16; ++i) { sc[i] = __expf(sc[i] - mx); sum += sc[i]; }
    sum += __shfl_xor(sum, 1);
    sum += __shfl_xor(sum, 2);
    const float inv = 1.0f / sum;
#pragma unroll
    for (int i = 0; i < 16; ++i) sc[i] *= inv;

    {
        size_t wbase = ((((size_t)b * HH + h) * SS + s) * NN + n) * NN + (size_t)qq * 16;
        if constexpr (F32) {
            float* wf = (float*)outv + (size_t)OUT0_ELEMS + wbase;
#pragma unroll
            for (int g = 0; g < 4; ++g) {
                float4 f; f.x = sc[g*4]; f.y = sc[g*4+1]; f.z = sc[g*4+2]; f.w = sc[g*4+3];
                *(float4*)(wf + g * 4) = f;
            }
        } else {
            u16* wo = (u16*)outv + (size_t)OUT0_ELEMS + wbase;
            union { u16 u[16]; uint4 v[2]; } wb;
#pragma unroll
            for (int i = 0; i < 16; ++i) wb.u[i] = f2bf(sc[i]);
            *(uint4*)wo = wb.v[0];
            *(uint4*)(wo + 8) = wb.v[1];
        }
    }

    float ao[32];
#pragma unroll
    for (int d = 0; d < 32; ++d) ao[d] = 0.f;
#pragma unroll
    for (int i = 0; i < 16; ++i) {
        int m = qq * 16 + i;
        float w = sc[i];
        const float* vr = &sV[ro(m)];
#pragma unroll
        for (int j = 0; j < 8; ++j) {
            float4 f = *(const float4*)(vr + j * 4);
            ao[j * 4 + 0] += w * f.x; ao[j * 4 + 1] += w * f.y;
            ao[j * 4 + 2] += w * f.z; ao[j * 4 + 3] += w * f.w;
        }
    }
#pragma unroll
    for (int d = 0; d < 32; ++d) {
        ao[d] += __shfl_xor(ao[d], 1);
        ao[d] += __shfl_xor(ao[d], 2);
    }
    {
        size_t abase = ((size_t)bs * NN + n) * DKK + h * DHH + (size_t)qq * 8;
        if constexpr (F32) {
            float* af = (float*)outv + abase;
            float4 f0, f1;
            f0.x = ao[qq*8+0]; f0.y = ao[qq*8+1]; f0.z = ao[qq*8+2]; f0.w = ao[qq*8+3];
            f1.x = ao[qq*8+4]; f1.y = ao[qq*8+5]; f1.z = ao[qq*8+6]; f1.w = ao[qq*8+7];
            *(float4*)af = f0;
            *(float4*)(af + 4) = f1;
        } else {
            union { u16 u[8]; uint4 v; } ob;
#pragma unroll
            for (int u = 0; u < 8; ++u) ob.u[u] = f2bf(ao[qq * 8 + u]);
            *(uint4*)((u16*)outv + abase) = ob.v;
        }
    }
}

// ---------------------------------------------------------------------------
// MFMA out-projection, 2-column ILP, fragment-major B (coalesced 1KB bursts).
// ---------------------------------------------------------------------------
template <bool F32>
__global__ __launch_bounds__(256) void k_outproj_mfma(
    const void* __restrict__ ws, const void* __restrict__ bOv,
    void* __restrict__ outv, const int* __restrict__ flag)
{
    if ((flag[0] != 0) != F32) return;

    const int t = threadIdx.x;
    const int wv_ = t >> 6, lane = t & 63, li = lane & 15, lg = lane >> 4;
    const size_t base = (size_t)blockIdx.x * (NN * DKK);
    const u16* wo_ = (const u16*)((const char*)ws + 512) + (size_t)3 * 65536 + lane * 8;

    short8 a[8];
    const size_t arow = base + (size_t)(wv_ * 16 + li) * 256;
    if constexpr (F32) {
        float4 X0[8], X1[8];
        const float* xp0 = (const float*)outv + arow + lg * 8;
#pragma unroll
        for (int ks = 0; ks < 8; ++ks) {
            X0[ks] = *(const float4*)(xp0 + ks * 32);
            X1[ks] = *(const float4*)(xp0 + ks * 32 + 4);
        }
#pragma unroll
        for (int ks = 0; ks < 8; ++ks) {
            float x8[8] = {X0[ks].x, X0[ks].y, X0[ks].z, X0[ks].w,
                           X1[ks].x, X1[ks].y, X1[ks].z, X1[ks].w};
#pragma unroll
            for (int j = 0; j < 8; ++j) a[ks][j] = (short)f2bf_hw(x8[j]);
        }
    } else {
#pragma unroll
        for (int ks = 0; ks < 8; ++ks) {
            const int kof = ks * 32 + lg * 8;
            a[ks] = *(const short8*)((const u16*)outv + arow + kof);
        }
    }

    for (int nt = 0; nt < 16; nt += 2) {
        const int colA = nt * 16 + li;
        const int colB = colA + 16;
        float bvA, bvB;
        if constexpr (F32) {
            bvA = ((const float*)bOv)[colA];
            bvB = ((const float*)bOv)[colB];
        } else {
            bvA = bf2f(((const u16*)bOv)[colA]);
            bvB = bf2f(((const u16*)bOv)[colB]);
        }
        f32x4 cA = {bvA, bvA, bvA, bvA};
        f32x4 cB = {bvB, bvB, bvB, bvB};
#pragma unroll
        for (int ks = 0; ks < 8; ++ks) {
            const u16* bb = wo_ + nt * 4096 + ks * 512;
            short8 bhA = *(const short8*)(bb);
            short8 bhB = *(const short8*)(bb + 4096);
            cA = __builtin_amdgcn_mfma_f32_16x16x32_bf16(a[ks], bhA, cA, 0, 0, 0);
            cB = __builtin_amdgcn_mfma_f32_16x16x32_bf16(a[ks], bhB, cB, 0, 0, 0);
            if constexpr (F32) {
                short8 blA = *(const short8*)(bb + 262144);
                short8 blB = *(const short8*)(bb + 262144 + 4096);
                cA = __builtin_amdgcn_mfma_f32_16x16x32_bf16(a[ks], blA, cA, 0, 0, 0);
                cB = __builtin_amdgcn_mfma_f32_16x16x32_bf16(a[ks], blB, cB, 0, 0, 0);
            }
        }
#pragma unroll
        for (int r = 0; r < 4; ++r) {
            size_t offA = base + (size_t)(wv_ * 16 + lg * 4 + r) * 256 + colA;
            if constexpr (F32) {
                ((float*)outv)[offA] = cA[r];
                ((float*)outv)[offA + 16] = cB[r];
            } else {
                ((u16*)outv)[offA] = f2bf(cA[r]);
                ((u16*)outv)[offA + 16] = f2bf(cB[r]);
            }
        }
    }
}

extern "C" void kernel_launch(void* const* d_in, const int* in_sizes, int n_in,
                              void* d_out, int out_size, void* d_ws, size_t ws_size,
                              hipStream_t stream) {
    (void)in_sizes; (void)n_in; (void)out_size;
    int* flag = (int*)d_ws;

    k_detect<<<1, 256, 0, stream>>>((const u16*)d_in[3], flag);

    if (ws_size >= WS_FULL) {
        k_wt<<<64, 256, 0, stream>>>(d_in[3], d_in[5], d_in[7], d_in[9], d_ws, flag);

        k_proj<false><<<BB * SS, 256, 0, stream>>>(
            d_in[0], d_in[1], d_in[2], d_in[4], d_in[6], d_in[8], d_ws, flag);
        k_proj<true><<<BB * SS, 256, 0, stream>>>(
            d_in[0], d_in[1], d_in[2], d_in[4], d_in[6], d_in[8], d_ws, flag);

        k_attn_ep<false><<<BB * SS * HH, 256, 0, stream>>>(d_ws, d_out, flag);
        k_attn_ep<true><<<BB * SS * HH, 256, 0, stream>>>(d_ws, d_out, flag);

        k_outproj_mfma<false><<<BB * SS, 256, 0, stream>>>(d_ws, d_in[10], d_out, flag);
        k_outproj_mfma<true><<<BB * SS, 256, 0, stream>>>(d_ws, d_in[10], d_out, flag);
    } else if (ws_size >= WS_WT) {
        k_wt<<<64, 256, 0, stream>>>(d_in[3], d_in[5], d_in[7], d_in[9], d_ws, flag);

        k_attn_mfma<false><<<BB * SS * HH, 256, 0, stream>>>(
            d_in[0], d_in[1], d_in[2], d_in[4], d_in[6], d_in[8],
            d_ws, d_out, flag);
        k_attn_mfma<true><<<BB * SS * HH, 256, 0, stream>>>(
            d_in[0], d_in[1], d_in[2], d_in[4], d_in[6], d_in[8],
            d_ws, d_out, flag);

        k_outproj_mfma<false><<<BB * SS, 256, 0, stream>>>(d_ws, d_in[10], d_out, flag);
        k_outproj_mfma<true><<<BB * SS, 256, 0, stream>>>(d_ws, d_in[10], d_out, flag);
    }
}